// Round 1
// baseline (1394.360 us; speedup 1.0000x reference)
//
#include <hip/hip_runtime.h>

#define IN_DIM 384
#define HID    128

// ---------------- utility ----------------
__global__ void zero_i32(int* __restrict__ p, int n) {
  int i = blockIdx.x * 256 + threadIdx.x;
  if (i < n) p[i] = 0;
}

// ---------------- degree count ----------------
__global__ void count_kernel(const int* __restrict__ dst, int E, int* __restrict__ cnt) {
  int e = blockIdx.x * 256 + threadIdx.x;
  if (e < E) atomicAdd(&cnt[dst[e]], 1);
}

// ---------------- 3-phase exclusive scan (chunk=256) ----------------
__global__ void scan1(const int* __restrict__ cnt, int N,
                      int* __restrict__ rs, int* __restrict__ partial) {
  __shared__ int s[256];
  int t = threadIdx.x;
  int i = blockIdx.x * 256 + t;
  int v = (i < N) ? cnt[i] : 0;
  s[t] = v;
  __syncthreads();
  for (int off = 1; off < 256; off <<= 1) {
    int y = (t >= off) ? s[t - off] : 0;
    __syncthreads();
    s[t] += y;
    __syncthreads();
  }
  rs[i] = s[t] - v;  // exclusive within chunk
  if (t == 255) partial[blockIdx.x] = s[255];
}

__global__ void scan2(const int* __restrict__ partial, int nb, int* __restrict__ base) {
  __shared__ int s[512];
  int t = threadIdx.x;
  int v = (t < nb) ? partial[t] : 0;
  s[t] = v;
  __syncthreads();
  for (int off = 1; off < 512; off <<= 1) {
    int y = (t >= off) ? s[t - off] : 0;
    __syncthreads();
    s[t] += y;
    __syncthreads();
  }
  if (t < nb) base[t] = s[t] - v;  // exclusive
}

__global__ void scan3(int* __restrict__ rs, int* __restrict__ cursor,
                      const int* __restrict__ base, int N) {
  int i = blockIdx.x * 256 + threadIdx.x;
  if (i < N) {
    int v = rs[i] + base[blockIdx.x];
    rs[i] = v;
    cursor[i] = v;
  }
}

// ---------------- counting-sort scatter: CSR adjacency ----------------
__global__ void fill_kernel(const int* __restrict__ src, const int* __restrict__ dst, int E,
                            int* __restrict__ cursor, int* __restrict__ sorted_src) {
  int e = blockIdx.x * 256 + threadIdx.x;
  if (e < E) {
    int p = atomicAdd(&cursor[dst[e]], 1);
    sorted_src[p] = src[e];
  }
}

// ---------------- fp32 dual-B GEMM: C[M x 256] = A[M x K] @ [Bl | Br] ----------------
// Bl, Br each [K x 128] row-major. BM=BN=64, BK=16, 256 threads, 4x4 micro-tile.
__global__ __launch_bounds__(256) void gemm_dual(
    const float* __restrict__ A, int M, int K,
    const float* __restrict__ Bl, const float* __restrict__ Br,
    float* __restrict__ C) {
  __shared__ float As[16][64];  // transposed: As[k][m]
  __shared__ float Bs[16][64];

  const int tid = threadIdx.x;
  const int row0 = blockIdx.x * 64;
  const int nb = blockIdx.y;                       // 0..3 -> C cols [nb*64, nb*64+64)
  const float* __restrict__ B = (nb < 2) ? Bl : Br;
  const int colBase = (nb & 1) * 64;               // col within the 128-wide B
  const int cBase = nb * 64;

  const int arow = tid >> 2;          // 0..63
  const int acol = (tid & 3) << 2;    // 0,4,8,12
  const int brow = tid >> 4;          // 0..15
  const int bcol = (tid & 15) << 2;   // 0..60
  const int tx = (tid & 15) << 2;     // 4 output cols
  const int ty = (tid >> 4) << 2;     // 4 output rows

  float acc[4][4] = {{0.f}};

  for (int k0 = 0; k0 < K; k0 += 16) {
    float4 av = make_float4(0.f, 0.f, 0.f, 0.f);
    int gr = row0 + arow;
    if (gr < M) av = *(const float4*)(A + (size_t)gr * K + k0 + acol);
    As[acol + 0][arow] = av.x;
    As[acol + 1][arow] = av.y;
    As[acol + 2][arow] = av.z;
    As[acol + 3][arow] = av.w;
    float4 bv = *(const float4*)(B + (size_t)(k0 + brow) * HID + colBase + bcol);
    *(float4*)&Bs[brow][bcol] = bv;
    __syncthreads();
#pragma unroll
    for (int k = 0; k < 16; ++k) {
      float4 a = *(const float4*)&As[k][ty];
      float4 b = *(const float4*)&Bs[k][tx];
      acc[0][0] = fmaf(a.x, b.x, acc[0][0]);
      acc[0][1] = fmaf(a.x, b.y, acc[0][1]);
      acc[0][2] = fmaf(a.x, b.z, acc[0][2]);
      acc[0][3] = fmaf(a.x, b.w, acc[0][3]);
      acc[1][0] = fmaf(a.y, b.x, acc[1][0]);
      acc[1][1] = fmaf(a.y, b.y, acc[1][1]);
      acc[1][2] = fmaf(a.y, b.z, acc[1][2]);
      acc[1][3] = fmaf(a.y, b.w, acc[1][3]);
      acc[2][0] = fmaf(a.z, b.x, acc[2][0]);
      acc[2][1] = fmaf(a.z, b.y, acc[2][1]);
      acc[2][2] = fmaf(a.z, b.z, acc[2][2]);
      acc[2][3] = fmaf(a.z, b.w, acc[2][3]);
      acc[3][0] = fmaf(a.w, b.x, acc[3][0]);
      acc[3][1] = fmaf(a.w, b.y, acc[3][1]);
      acc[3][2] = fmaf(a.w, b.z, acc[3][2]);
      acc[3][3] = fmaf(a.w, b.w, acc[3][3]);
    }
    __syncthreads();
  }
#pragma unroll
  for (int i = 0; i < 4; ++i) {
    int gr = row0 + ty + i;
    if (gr < M)
      *(float4*)(C + (size_t)gr * 256 + cBase + tx) =
          make_float4(acc[i][0], acc[i][1], acc[i][2], acc[i][3]);
  }
}

// ---------------- layer-1 aggregate + combine + ReLU ----------------
// yz: [N x 256], cols 0..127 = x@W_l, 128..255 = x@W_r
__global__ __launch_bounds__(128) void agg_relu(
    const float* __restrict__ yz, const int* __restrict__ sorted_src,
    const int* __restrict__ rs, const int* __restrict__ cnt,
    const float* __restrict__ bias, float* __restrict__ h) {
  __shared__ int sidx[128];
  const int node = blockIdx.x;
  const int d = threadIdx.x;
  const int start = rs[node];
  const int deg = cnt[node];
  float acc = 0.f;
  for (int k0 = 0; k0 < deg; k0 += 128) {
    int kk = k0 + d;
    sidx[d] = (kk < deg) ? sorted_src[start + kk] : 0;
    __syncthreads();
    int lim = min(128, deg - k0);
    for (int k = 0; k < lim; ++k) acc += yz[(size_t)sidx[k] * 256 + d];
    __syncthreads();
  }
  float v = acc / (float)max(deg, 1) + bias[d] + yz[(size_t)node * 256 + 128 + d];
  h[(size_t)node * 128 + d] = fmaxf(v, 0.f);
}

// ---------------- layer-2 aggregate + combine + fused scorer projection ----------------
// Emits s_a[n] = h2[n] . Wlin[0:128], s_b[n] = h2[n] . Wlin[128:256]; h2 never stored.
__global__ __launch_bounds__(128) void agg_score(
    const float* __restrict__ yz, const int* __restrict__ sorted_src,
    const int* __restrict__ rs, const int* __restrict__ cnt,
    const float* __restrict__ bias, const float* __restrict__ Wlin,
    float* __restrict__ sa, float* __restrict__ sb) {
  __shared__ int sidx[128];
  __shared__ float red[4];
  const int node = blockIdx.x;
  const int d = threadIdx.x;
  const int start = rs[node];
  const int deg = cnt[node];
  float acc = 0.f;
  for (int k0 = 0; k0 < deg; k0 += 128) {
    int kk = k0 + d;
    sidx[d] = (kk < deg) ? sorted_src[start + kk] : 0;
    __syncthreads();
    int lim = min(128, deg - k0);
    for (int k = 0; k < lim; ++k) acc += yz[(size_t)sidx[k] * 256 + d];
    __syncthreads();
  }
  float h2 = acc / (float)max(deg, 1) + bias[d] + yz[(size_t)node * 256 + 128 + d];
  float pa = h2 * Wlin[d];
  float pb = h2 * Wlin[128 + d];
#pragma unroll
  for (int off = 32; off > 0; off >>= 1) {
    pa += __shfl_down(pa, off, 64);
    pb += __shfl_down(pb, off, 64);
  }
  if ((d & 63) == 0) {
    red[(d >> 6) * 2] = pa;
    red[(d >> 6) * 2 + 1] = pb;
  }
  __syncthreads();
  if (d == 0) {
    sa[node] = red[0] + red[2];
    sb[node] = red[1] + red[3];
  }
}

// ---------------- edge scoring: out[e] = s_a[i] + s_b[j] + b ----------------
__global__ void score_kernel(const int* __restrict__ idx, int E,
                             const float* __restrict__ sa, const float* __restrict__ sb,
                             const float* __restrict__ blin, float* __restrict__ out) {
  int e = blockIdx.x * 256 + threadIdx.x;
  if (e < E) out[e] = sa[idx[e]] + sb[idx[E + e]] + blin[0];
}

extern "C" void kernel_launch(void* const* d_in, const int* in_sizes, int n_in,
                              void* d_out, int out_size, void* d_ws, size_t ws_size,
                              hipStream_t stream) {
  (void)n_in; (void)out_size; (void)ws_size;
  const float* x    = (const float*)d_in[0];
  const int*   ei   = (const int*)d_in[1];
  const int*   pos  = (const int*)d_in[2];
  const int*   neg  = (const int*)d_in[3];
  const float* Wl1  = (const float*)d_in[4];
  const float* bl1  = (const float*)d_in[5];
  const float* Wr1  = (const float*)d_in[6];
  const float* Wl2  = (const float*)d_in[7];
  const float* bl2  = (const float*)d_in[8];
  const float* Wr2  = (const float*)d_in[9];
  const float* Wlin = (const float*)d_in[10];
  const float* blin = (const float*)d_in[11];

  const int N  = in_sizes[0] / IN_DIM;  // 100000
  const int E  = in_sizes[1] / 2;       // 3200000
  const int Ep = in_sizes[2] / 2;       // 500000
  const int En = in_sizes[3] / 2;       // 500000
  const int* e_src = ei;
  const int* e_dst = ei + E;

  // workspace carve (256B aligned); total ~168.5 MB
  char* ws = (char*)d_ws;
  size_t off = 0;
  auto carve = [&](size_t bytes) -> char* {
    char* p = ws + off;
    off += (bytes + 255) & ~(size_t)255;
    return p;
  };
  const int nbN = (N + 255) / 256;   // 391
  const int NPAD = nbN * 256;        // 100096
  int*   cnt    = (int*)carve((size_t)NPAD * 4);
  int*   rs     = (int*)carve((size_t)NPAD * 4);
  int*   cursor = (int*)carve((size_t)NPAD * 4);
  int*   partial= (int*)carve(512 * 4);
  int*   base   = (int*)carve(512 * 4);
  int*   sorted = (int*)carve((size_t)E * 4);
  float* sa     = (float*)carve((size_t)N * 4);
  float* sb     = (float*)carve((size_t)N * 4);
  float* yz     = (float*)carve((size_t)N * 256 * 4);  // layer1 [y|z], reused for layer2
  float* h1     = (float*)carve((size_t)N * 128 * 4);

  const int nbE = (E + 255) / 256;

  hipLaunchKernelGGL(zero_i32, dim3(nbN), dim3(256), 0, stream, cnt, NPAD);
  hipLaunchKernelGGL(count_kernel, dim3(nbE), dim3(256), 0, stream, e_dst, E, cnt);
  hipLaunchKernelGGL(scan1, dim3(nbN), dim3(256), 0, stream, cnt, N, rs, partial);
  hipLaunchKernelGGL(scan2, dim3(1), dim3(512), 0, stream, partial, nbN, base);
  hipLaunchKernelGGL(scan3, dim3(nbN), dim3(256), 0, stream, rs, cursor, base, N);
  hipLaunchKernelGGL(fill_kernel, dim3(nbE), dim3(256), 0, stream, e_src, e_dst, E, cursor, sorted);

  hipLaunchKernelGGL(gemm_dual, dim3((N + 63) / 64, 4), dim3(256), 0, stream,
                     x, N, IN_DIM, Wl1, Wr1, yz);
  hipLaunchKernelGGL(agg_relu, dim3(N), dim3(128), 0, stream, yz, sorted, rs, cnt, bl1, h1);
  hipLaunchKernelGGL(gemm_dual, dim3((N + 63) / 64, 4), dim3(256), 0, stream,
                     h1, N, HID, Wl2, Wr2, yz);
  hipLaunchKernelGGL(agg_score, dim3(N), dim3(128), 0, stream, yz, sorted, rs, cnt, bl2, Wlin, sa, sb);

  float* out = (float*)d_out;
  hipLaunchKernelGGL(score_kernel, dim3((Ep + 255) / 256), dim3(256), 0, stream,
                     pos, Ep, sa, sb, blin, out);
  hipLaunchKernelGGL(score_kernel, dim3((En + 255) / 256), dim3(256), 0, stream,
                     neg, En, sa, sb, blin, out + Ep);
}

// Round 2
// 959.787 us; speedup vs baseline: 1.4528x; 1.4528x over previous
//
#include <hip/hip_runtime.h>

#define IN_DIM 384
#define HID    128

typedef _Float16 half8 __attribute__((ext_vector_type(8)));
typedef float floatx4 __attribute__((ext_vector_type(4)));

// ---------------- utility ----------------
__global__ void zero_i32(int* __restrict__ p, int n) {
  int i = blockIdx.x * 256 + threadIdx.x;
  if (i < n) p[i] = 0;
}

// ---------------- degree count ----------------
__global__ void count_kernel(const int* __restrict__ dst, int E, int* __restrict__ cnt) {
  int e = blockIdx.x * 256 + threadIdx.x;
  if (e < E) atomicAdd(&cnt[dst[e]], 1);
}

// ---------------- 3-phase exclusive scan (chunk=256) ----------------
__global__ void scan1(const int* __restrict__ cnt, int N,
                      int* __restrict__ rs, int* __restrict__ partial) {
  __shared__ int s[256];
  int t = threadIdx.x;
  int i = blockIdx.x * 256 + t;
  int v = (i < N) ? cnt[i] : 0;
  s[t] = v;
  __syncthreads();
  for (int off = 1; off < 256; off <<= 1) {
    int y = (t >= off) ? s[t - off] : 0;
    __syncthreads();
    s[t] += y;
    __syncthreads();
  }
  rs[i] = s[t] - v;  // exclusive within chunk
  if (t == 255) partial[blockIdx.x] = s[255];
}

__global__ void scan2(const int* __restrict__ partial, int nb, int* __restrict__ base) {
  __shared__ int s[512];
  int t = threadIdx.x;
  int v = (t < nb) ? partial[t] : 0;
  s[t] = v;
  __syncthreads();
  for (int off = 1; off < 512; off <<= 1) {
    int y = (t >= off) ? s[t - off] : 0;
    __syncthreads();
    s[t] += y;
    __syncthreads();
  }
  if (t < nb) base[t] = s[t] - v;  // exclusive
}

__global__ void scan3(int* __restrict__ rs, int* __restrict__ cursor,
                      const int* __restrict__ base, int N) {
  int i = blockIdx.x * 256 + threadIdx.x;
  if (i < N) {
    int v = rs[i] + base[blockIdx.x];
    rs[i] = v;
    cursor[i] = v;
  }
}

// ---------------- counting-sort scatter: CSR adjacency ----------------
__global__ void fill_kernel(const int* __restrict__ src, const int* __restrict__ dst, int E,
                            int* __restrict__ cursor, int* __restrict__ sorted_src) {
  int e = blockIdx.x * 256 + threadIdx.x;
  if (e < E) {
    int p = atomicAdd(&cursor[dst[e]], 1);
    sorted_src[p] = src[e];
  }
}

// ---------------- weight pack: W[K][128] fp32 -> per-lane MFMA B-fragment order ----------------
// Bp layout: [tile_n(16 total over both halves)][ks][lane(64)][8 halves]
// For mfma_f32_16x16x32_f16 B operand: lane holds B[k = (lane>>4)*8 + j][n = lane&15].
__global__ void pack_w(const float* __restrict__ W, _Float16* __restrict__ Bp,
                       int tnBase) {
  const int tn = blockIdx.x;       // 0..7 within this half
  const int ks = blockIdx.y;       // 0..KS-1
  const int KS = gridDim.y;
  const int lane = threadIdx.x;    // 0..63
  const int n = tn * 16 + (lane & 15);
  const int kb = ks * 32 + (lane >> 4) * 8;
  half8 v;
#pragma unroll
  for (int j = 0; j < 8; ++j) v[j] = (_Float16)W[(size_t)(kb + j) * HID + n];
  *(half8*)(Bp + (((size_t)(tnBase + tn) * KS + ks) * 64 + lane) * 8) = v;
}

// ---------------- fp16 MFMA GEMM: C[M x 256] = A[M x K] @ [Bl | Br] ----------------
// Block: 128 rows x 256 cols, 512 threads (8 waves), wave = 64x64 via 4x4 of 16x16x32.
// A from fp32 (A32) or fp16 (A16); C stored fp16.
__global__ __launch_bounds__(512) void gemm_f16(
    const float* __restrict__ A32, const _Float16* __restrict__ A16,
    int M, int K,
    const _Float16* __restrict__ Bp,
    _Float16* __restrict__ C) {
  __shared__ _Float16 As[128][40];   // stride 40 halves = 80 B: 2-way bank alias (free)

  const int KS = K >> 5;
  const int tid = threadIdx.x;
  const int lane = tid & 63;
  const int wid = tid >> 6;
  const int quad = lane >> 4;
  const int lm = lane & 15;
  const int row0 = (wid & 1) * 64;       // wave row base within block
  const int ct0 = (wid >> 1) * 4;        // wave col-tile base (16-wide tiles)
  const int blockRow = blockIdx.x * 128;

  const int srow = tid >> 2;             // staging: row 0..127
  const int scol = (tid & 3) * 8;        // staging: col 0,8,16,24

  floatx4 acc[16];
#pragma unroll
  for (int i = 0; i < 16; ++i) {
    acc[i][0] = 0.f; acc[i][1] = 0.f; acc[i][2] = 0.f; acc[i][3] = 0.f;
  }

  for (int ks = 0; ks < KS; ++ks) {
    // ---- stage A tile (128 x 32) into LDS as fp16 ----
    const int gr = blockRow + srow;
    half8 hv;
    if (A32) {
      float4 f0 = make_float4(0.f, 0.f, 0.f, 0.f), f1 = f0;
      if (gr < M) {
        const float* p = A32 + (size_t)gr * K + ks * 32 + scol;
        f0 = *(const float4*)p;
        f1 = *(const float4*)(p + 4);
      }
      hv[0] = (_Float16)f0.x; hv[1] = (_Float16)f0.y;
      hv[2] = (_Float16)f0.z; hv[3] = (_Float16)f0.w;
      hv[4] = (_Float16)f1.x; hv[5] = (_Float16)f1.y;
      hv[6] = (_Float16)f1.z; hv[7] = (_Float16)f1.w;
    } else {
      if (gr < M) {
        hv = *(const half8*)(A16 + (size_t)gr * K + ks * 32 + scol);
      } else {
#pragma unroll
        for (int j = 0; j < 8; ++j) hv[j] = (_Float16)0.f;
      }
    }
    __syncthreads();   // previous iteration's LDS reads complete
    *(half8*)&As[srow][scol] = hv;
    __syncthreads();   // staging visible

    // ---- fragments ----
    half8 af[4], bf[4];
#pragma unroll
    for (int rt = 0; rt < 4; ++rt)
      af[rt] = *(const half8*)&As[row0 + rt * 16 + lm][quad * 8];
#pragma unroll
    for (int ct = 0; ct < 4; ++ct) {
      const int tn = ct0 + ct;
      bf[ct] = *(const half8*)(Bp + (((size_t)tn * KS + ks) * 64 + lane) * 8);
    }
#pragma unroll
    for (int rt = 0; rt < 4; ++rt)
#pragma unroll
      for (int ct = 0; ct < 4; ++ct)
        acc[rt * 4 + ct] =
            __builtin_amdgcn_mfma_f32_16x16x32_f16(af[rt], bf[ct], acc[rt * 4 + ct], 0, 0, 0);
  }

  // ---- epilogue: C/D layout col=lane&15, row=quad*4+reg ----
#pragma unroll
  for (int rt = 0; rt < 4; ++rt) {
#pragma unroll
    for (int r = 0; r < 4; ++r) {
      const int gm = blockRow + row0 + rt * 16 + quad * 4 + r;
      if (gm < M) {
#pragma unroll
        for (int ct = 0; ct < 4; ++ct) {
          const int col = (ct0 + ct) * 16 + lm;
          C[(size_t)gm * 256 + col] = (_Float16)acc[rt * 4 + ct][r];
        }
      }
    }
  }
}

// ---------------- layer-1 aggregate + combine + ReLU (fp16 activations) ----------------
// yz: [N x 256] fp16, cols 0..127 = x@W_l, 128..255 = x@W_r
__global__ __launch_bounds__(128) void agg_relu16(
    const _Float16* __restrict__ yz, const int* __restrict__ sorted_src,
    const int* __restrict__ rs, const int* __restrict__ cnt,
    const float* __restrict__ bias, _Float16* __restrict__ h) {
  __shared__ int sidx[128];
  const int node = blockIdx.x;
  const int d = threadIdx.x;
  const int start = rs[node];
  const int deg = cnt[node];
  float acc = 0.f;
  for (int k0 = 0; k0 < deg; k0 += 128) {
    int kk = k0 + d;
    sidx[d] = (kk < deg) ? sorted_src[start + kk] : 0;
    __syncthreads();
    int lim = min(128, deg - k0);
    for (int k = 0; k < lim; ++k) acc += (float)yz[(size_t)sidx[k] * 256 + d];
    __syncthreads();
  }
  float v = acc / (float)max(deg, 1) + bias[d] + (float)yz[(size_t)node * 256 + 128 + d];
  h[(size_t)node * 128 + d] = (_Float16)fmaxf(v, 0.f);
}

// ---------------- layer-2 aggregate + combine + fused scorer projection ----------------
__global__ __launch_bounds__(128) void agg_score16(
    const _Float16* __restrict__ yz, const int* __restrict__ sorted_src,
    const int* __restrict__ rs, const int* __restrict__ cnt,
    const float* __restrict__ bias, const float* __restrict__ Wlin,
    float* __restrict__ sa, float* __restrict__ sb) {
  __shared__ int sidx[128];
  __shared__ float red[4];
  const int node = blockIdx.x;
  const int d = threadIdx.x;
  const int start = rs[node];
  const int deg = cnt[node];
  float acc = 0.f;
  for (int k0 = 0; k0 < deg; k0 += 128) {
    int kk = k0 + d;
    sidx[d] = (kk < deg) ? sorted_src[start + kk] : 0;
    __syncthreads();
    int lim = min(128, deg - k0);
    for (int k = 0; k < lim; ++k) acc += (float)yz[(size_t)sidx[k] * 256 + d];
    __syncthreads();
  }
  float h2 = acc / (float)max(deg, 1) + bias[d] + (float)yz[(size_t)node * 256 + 128 + d];
  float pa = h2 * Wlin[d];
  float pb = h2 * Wlin[128 + d];
#pragma unroll
  for (int off = 32; off > 0; off >>= 1) {
    pa += __shfl_down(pa, off, 64);
    pb += __shfl_down(pb, off, 64);
  }
  if ((d & 63) == 0) {
    red[(d >> 6) * 2] = pa;
    red[(d >> 6) * 2 + 1] = pb;
  }
  __syncthreads();
  if (d == 0) {
    sa[node] = red[0] + red[2];
    sb[node] = red[1] + red[3];
  }
}

// ---------------- edge scoring: out[e] = s_a[i] + s_b[j] + b ----------------
__global__ void score_kernel(const int* __restrict__ idx, int E,
                             const float* __restrict__ sa, const float* __restrict__ sb,
                             const float* __restrict__ blin, float* __restrict__ out) {
  int e = blockIdx.x * 256 + threadIdx.x;
  if (e < E) out[e] = sa[idx[e]] + sb[idx[E + e]] + blin[0];
}

extern "C" void kernel_launch(void* const* d_in, const int* in_sizes, int n_in,
                              void* d_out, int out_size, void* d_ws, size_t ws_size,
                              hipStream_t stream) {
  (void)n_in; (void)out_size; (void)ws_size;
  const float* x    = (const float*)d_in[0];
  const int*   ei   = (const int*)d_in[1];
  const int*   pos  = (const int*)d_in[2];
  const int*   neg  = (const int*)d_in[3];
  const float* Wl1  = (const float*)d_in[4];
  const float* bl1  = (const float*)d_in[5];
  const float* Wr1  = (const float*)d_in[6];
  const float* Wl2  = (const float*)d_in[7];
  const float* bl2  = (const float*)d_in[8];
  const float* Wr2  = (const float*)d_in[9];
  const float* Wlin = (const float*)d_in[10];
  const float* blin = (const float*)d_in[11];

  const int N  = in_sizes[0] / IN_DIM;  // 100000
  const int E  = in_sizes[1] / 2;       // 3200000
  const int Ep = in_sizes[2] / 2;       // 500000
  const int En = in_sizes[3] / 2;       // 500000
  const int* e_src = ei;
  const int* e_dst = ei + E;

  // workspace carve (256B aligned)
  char* ws = (char*)d_ws;
  size_t off = 0;
  auto carve = [&](size_t bytes) -> char* {
    char* p = ws + off;
    off += (bytes + 255) & ~(size_t)255;
    return p;
  };
  const int nbN = (N + 255) / 256;   // 391
  const int NPAD = nbN * 256;        // 100096
  const int KS1 = IN_DIM / 32;       // 12
  const int KS2 = HID / 32;          // 4

  int*      cnt    = (int*)carve((size_t)NPAD * 4);
  int*      rs     = (int*)carve((size_t)NPAD * 4);
  int*      cursor = (int*)carve((size_t)NPAD * 4);
  int*      partial= (int*)carve(512 * 4);
  int*      base   = (int*)carve(512 * 4);
  int*      sorted = (int*)carve((size_t)E * 4);
  float*    sa     = (float*)carve((size_t)N * 4);
  float*    sb     = (float*)carve((size_t)N * 4);
  _Float16* Bp1    = (_Float16*)carve((size_t)16 * KS1 * 64 * 8 * 2);
  _Float16* Bp2    = (_Float16*)carve((size_t)16 * KS2 * 64 * 8 * 2);
  _Float16* yz     = (_Float16*)carve((size_t)N * 256 * 2);  // [y|z], reused for layer2
  _Float16* h1     = (_Float16*)carve((size_t)N * 128 * 2);

  const int nbE = (E + 255) / 256;
  const int gemmBlocks = (N + 127) / 128;

  // CSR build
  hipLaunchKernelGGL(zero_i32, dim3(nbN), dim3(256), 0, stream, cnt, NPAD);
  hipLaunchKernelGGL(count_kernel, dim3(nbE), dim3(256), 0, stream, e_dst, E, cnt);
  hipLaunchKernelGGL(scan1, dim3(nbN), dim3(256), 0, stream, cnt, N, rs, partial);
  hipLaunchKernelGGL(scan2, dim3(1), dim3(512), 0, stream, partial, nbN, base);
  hipLaunchKernelGGL(scan3, dim3(nbN), dim3(256), 0, stream, rs, cursor, base, N);
  hipLaunchKernelGGL(fill_kernel, dim3(nbE), dim3(256), 0, stream, e_src, e_dst, E, cursor, sorted);

  // weight packing (tiny)
  hipLaunchKernelGGL(pack_w, dim3(8, KS1), dim3(64), 0, stream, Wl1, Bp1, 0);
  hipLaunchKernelGGL(pack_w, dim3(8, KS1), dim3(64), 0, stream, Wr1, Bp1, 8);
  hipLaunchKernelGGL(pack_w, dim3(8, KS2), dim3(64), 0, stream, Wl2, Bp2, 0);
  hipLaunchKernelGGL(pack_w, dim3(8, KS2), dim3(64), 0, stream, Wr2, Bp2, 8);

  // layer 1
  hipLaunchKernelGGL(gemm_f16, dim3(gemmBlocks), dim3(512), 0, stream,
                     x, (const _Float16*)nullptr, N, IN_DIM, Bp1, yz);
  hipLaunchKernelGGL(agg_relu16, dim3(N), dim3(128), 0, stream,
                     yz, sorted, rs, cnt, bl1, h1);
  // layer 2
  hipLaunchKernelGGL(gemm_f16, dim3(gemmBlocks), dim3(512), 0, stream,
                     (const float*)nullptr, h1, N, HID, Bp2, yz);
  hipLaunchKernelGGL(agg_score16, dim3(N), dim3(128), 0, stream,
                     yz, sorted, rs, cnt, bl2, Wlin, sa, sb);

  // scoring
  float* out = (float*)d_out;
  hipLaunchKernelGGL(score_kernel, dim3((Ep + 255) / 256), dim3(256), 0, stream,
                     pos, Ep, sa, sb, blin, out);
  hipLaunchKernelGGL(score_kernel, dim3((En + 255) / 256), dim3(256), 0, stream,
                     neg, En, sa, sb, blin, out + Ep);
}

// Round 3
// 776.877 us; speedup vs baseline: 1.7948x; 1.2354x over previous
//
#include <hip/hip_runtime.h>

#define IN_DIM 384
#define HID    128
#define NPB    256            // nodes per bucket (dstLocal fits in 8 bits)

typedef _Float16 half8 __attribute__((ext_vector_type(8)));
typedef float floatx4 __attribute__((ext_vector_type(4)));

// ---------------- utility ----------------
__global__ void zero_i32(int* __restrict__ p, int n) {
  int i = blockIdx.x * 256 + threadIdx.x;
  if (i < n) p[i] = 0;
}

// ---------------- degree count ----------------
__global__ void count_kernel(const int* __restrict__ dst, int E, int* __restrict__ cnt) {
  int e = blockIdx.x * 256 + threadIdx.x;
  if (e < E) atomicAdd(&cnt[dst[e]], 1);
}

// ---------------- 3-phase exclusive scan (chunk=256) ----------------
__global__ void scan1(const int* __restrict__ cnt, int N,
                      int* __restrict__ rs, int* __restrict__ partial) {
  __shared__ int s[256];
  int t = threadIdx.x;
  int i = blockIdx.x * 256 + t;
  int v = (i < N) ? cnt[i] : 0;
  s[t] = v;
  __syncthreads();
  for (int off = 1; off < 256; off <<= 1) {
    int y = (t >= off) ? s[t - off] : 0;
    __syncthreads();
    s[t] += y;
    __syncthreads();
  }
  rs[i] = s[t] - v;  // exclusive within chunk
  if (t == 255) partial[blockIdx.x] = s[255];
}

__global__ void scan2(const int* __restrict__ partial, int nb, int* __restrict__ base) {
  __shared__ int s[512];
  int t = threadIdx.x;
  int v = (t < nb) ? partial[t] : 0;
  s[t] = v;
  __syncthreads();
  for (int off = 1; off < 512; off <<= 1) {
    int y = (t >= off) ? s[t - off] : 0;
    __syncthreads();
    s[t] += y;
    __syncthreads();
  }
  if (t < nb) base[t] = s[t] - v;  // exclusive
}

__global__ void scan3(int* __restrict__ rs, const int* __restrict__ base, int N) {
  int i = blockIdx.x * 256 + threadIdx.x;
  if (i < N) rs[i] += base[blockIdx.x];
}

// ---------------- bucket cursor init: bucketCursor[b] = rs[b*NPB] ----------------
__global__ void init_buckets(const int* __restrict__ rs, int nB, int* __restrict__ bucketCursor) {
  int b = blockIdx.x * 256 + threadIdx.x;
  if (b < nB) bucketCursor[b] = rs[b * NPB];
}

// ---------------- phase 1: partition edges into coarse buckets ----------------
// 8192 edges/block; packed value = (dstLocal << 17) | src  (src < 2^17, dstLocal < 256)
__global__ __launch_bounds__(256) void partition_kernel(
    const int* __restrict__ src, const int* __restrict__ dst, int E, int nB,
    int* __restrict__ bucketCursor, unsigned* __restrict__ bucketData) {
  __shared__ int hist[391];
  __shared__ int gbase[391];
  const int t = threadIdx.x;
  const int b0 = blockIdx.x * 8192;

  for (int i = t; i < nB; i += 256) hist[i] = 0;
  __syncthreads();
#pragma unroll
  for (int i = 0; i < 32; ++i) {
    int e = b0 + i * 256 + t;
    if (e < E) atomicAdd(&hist[dst[e] >> 8], 1);
  }
  __syncthreads();
  for (int i = t; i < nB; i += 256) {
    int h = hist[i];
    gbase[i] = h ? atomicAdd(&bucketCursor[i], h) : 0;
    hist[i] = 0;
  }
  __syncthreads();
#pragma unroll
  for (int i = 0; i < 32; ++i) {
    int e = b0 + i * 256 + t;
    if (e < E) {
      int d = dst[e];
      int b = d >> 8;
      int r = atomicAdd(&hist[b], 1);
      bucketData[gbase[b] + r] = ((unsigned)(d & 255) << 17) | (unsigned)src[e];
    }
  }
}

// ---------------- phase 2: within-bucket node sort (writes confined to 32KB region) ----
__global__ __launch_bounds__(256) void node_sort(
    const unsigned* __restrict__ bucketData, const int* __restrict__ rs,
    int N, int E, int* __restrict__ sorted_src) {
  __shared__ int cur[NPB];
  const int b = blockIdx.x;
  const int t = threadIdx.x;
  const int node = b * NPB + t;
  cur[t] = (node < N) ? rs[node] : 0;
  __syncthreads();
  const int start = rs[b * NPB];
  const int end = (b == (int)gridDim.x - 1) ? E : rs[(b + 1) * NPB];
  for (int e = start + t; e < end; e += 256) {
    unsigned v = bucketData[e];
    int p = atomicAdd(&cur[v >> 17], 1);
    sorted_src[p] = (int)(v & 0x1FFFF);
  }
}

// ---------------- weight pack: W[K][128] fp32 -> per-lane MFMA B-fragment order ----------------
__global__ void pack_w(const float* __restrict__ W, _Float16* __restrict__ Bp,
                       int tnBase) {
  const int tn = blockIdx.x;       // 0..7 within this half
  const int ks = blockIdx.y;       // 0..KS-1
  const int KS = gridDim.y;
  const int lane = threadIdx.x;    // 0..63
  const int n = tn * 16 + (lane & 15);
  const int kb = ks * 32 + (lane >> 4) * 8;
  half8 v;
#pragma unroll
  for (int j = 0; j < 8; ++j) v[j] = (_Float16)W[(size_t)(kb + j) * HID + n];
  *(half8*)(Bp + (((size_t)(tnBase + tn) * KS + ks) * 64 + lane) * 8) = v;
}

// ---------------- fp16 MFMA GEMM: C[M x 256] = A[M x K] @ [Bl | Br] ----------------
__global__ __launch_bounds__(512) void gemm_f16(
    const float* __restrict__ A32, const _Float16* __restrict__ A16,
    int M, int K,
    const _Float16* __restrict__ Bp,
    _Float16* __restrict__ C) {
  __shared__ _Float16 As[128][40];

  const int KS = K >> 5;
  const int tid = threadIdx.x;
  const int lane = tid & 63;
  const int wid = tid >> 6;
  const int quad = lane >> 4;
  const int lm = lane & 15;
  const int row0 = (wid & 1) * 64;
  const int ct0 = (wid >> 1) * 4;
  const int blockRow = blockIdx.x * 128;

  const int srow = tid >> 2;
  const int scol = (tid & 3) * 8;

  floatx4 acc[16];
#pragma unroll
  for (int i = 0; i < 16; ++i) {
    acc[i][0] = 0.f; acc[i][1] = 0.f; acc[i][2] = 0.f; acc[i][3] = 0.f;
  }

  for (int ks = 0; ks < KS; ++ks) {
    const int gr = blockRow + srow;
    half8 hv;
    if (A32) {
      float4 f0 = make_float4(0.f, 0.f, 0.f, 0.f), f1 = f0;
      if (gr < M) {
        const float* p = A32 + (size_t)gr * K + ks * 32 + scol;
        f0 = *(const float4*)p;
        f1 = *(const float4*)(p + 4);
      }
      hv[0] = (_Float16)f0.x; hv[1] = (_Float16)f0.y;
      hv[2] = (_Float16)f0.z; hv[3] = (_Float16)f0.w;
      hv[4] = (_Float16)f1.x; hv[5] = (_Float16)f1.y;
      hv[6] = (_Float16)f1.z; hv[7] = (_Float16)f1.w;
    } else {
      if (gr < M) {
        hv = *(const half8*)(A16 + (size_t)gr * K + ks * 32 + scol);
      } else {
#pragma unroll
        for (int j = 0; j < 8; ++j) hv[j] = (_Float16)0.f;
      }
    }
    __syncthreads();
    *(half8*)&As[srow][scol] = hv;
    __syncthreads();

    half8 af[4], bf[4];
#pragma unroll
    for (int rt = 0; rt < 4; ++rt)
      af[rt] = *(const half8*)&As[row0 + rt * 16 + lm][quad * 8];
#pragma unroll
    for (int ct = 0; ct < 4; ++ct) {
      const int tn = ct0 + ct;
      bf[ct] = *(const half8*)(Bp + (((size_t)tn * KS + ks) * 64 + lane) * 8);
    }
#pragma unroll
    for (int rt = 0; rt < 4; ++rt)
#pragma unroll
      for (int ct = 0; ct < 4; ++ct)
        acc[rt * 4 + ct] =
            __builtin_amdgcn_mfma_f32_16x16x32_f16(af[rt], bf[ct], acc[rt * 4 + ct], 0, 0, 0);
  }

#pragma unroll
  for (int rt = 0; rt < 4; ++rt) {
#pragma unroll
    for (int r = 0; r < 4; ++r) {
      const int gm = blockRow + row0 + rt * 16 + quad * 4 + r;
      if (gm < M) {
#pragma unroll
        for (int ct = 0; ct < 4; ++ct) {
          const int col = (ct0 + ct) * 16 + lm;
          C[(size_t)gm * 256 + col] = (_Float16)acc[rt * 4 + ct][r];
        }
      }
    }
  }
}

// ---------------- helpers for fp16-pair math ----------------
__device__ inline float2 upk(unsigned u) {
  union { unsigned v; _Float16 h[2]; } c; c.v = u;
  return make_float2((float)c.h[0], (float)c.h[1]);
}

// ---------------- layer-1 aggregate + combine + ReLU ----------------
// yz viewed as u32: row stride 128 (= 256 fp16). 4 nodes/block, 64 lanes/node.
__global__ __launch_bounds__(256) void agg_relu16(
    const unsigned* __restrict__ yzu, const int* __restrict__ sorted_src,
    const int* __restrict__ rs, const int* __restrict__ cnt,
    const float* __restrict__ bias, unsigned* __restrict__ h1u, int N) {
  const int g = threadIdx.x >> 6;
  const int l = threadIdx.x & 63;
  const int node = blockIdx.x * 4 + g;
  if (node >= N) return;
  const int start = rs[node];
  const int deg = cnt[node];
  float2 acc = make_float2(0.f, 0.f);
  int k = 0;
  for (; k + 4 <= deg; k += 4) {
    int s0 = sorted_src[start + k];
    int s1 = sorted_src[start + k + 1];
    int s2 = sorted_src[start + k + 2];
    int s3 = sorted_src[start + k + 3];
    unsigned v0 = yzu[(size_t)s0 * 128 + l];
    unsigned v1 = yzu[(size_t)s1 * 128 + l];
    unsigned v2 = yzu[(size_t)s2 * 128 + l];
    unsigned v3 = yzu[(size_t)s3 * 128 + l];
    float2 f0 = upk(v0), f1 = upk(v1), f2 = upk(v2), f3 = upk(v3);
    acc.x += (f0.x + f1.x) + (f2.x + f3.x);
    acc.y += (f0.y + f1.y) + (f2.y + f3.y);
  }
  for (; k < deg; ++k) {
    float2 f = upk(yzu[(size_t)sorted_src[start + k] * 128 + l]);
    acc.x += f.x; acc.y += f.y;
  }
  const float inv = 1.f / (float)max(deg, 1);
  float2 z = upk(yzu[(size_t)node * 128 + 64 + l]);
  float vx = fmaxf(acc.x * inv + bias[2 * l] + z.x, 0.f);
  float vy = fmaxf(acc.y * inv + bias[2 * l + 1] + z.y, 0.f);
  union { unsigned v; _Float16 h[2]; } o;
  o.h[0] = (_Float16)vx; o.h[1] = (_Float16)vy;
  h1u[(size_t)node * 64 + l] = o.v;
}

// ---------------- layer-2 aggregate + combine + fused scorer projection ----------------
__global__ __launch_bounds__(256) void agg_score16(
    const unsigned* __restrict__ yzu, const int* __restrict__ sorted_src,
    const int* __restrict__ rs, const int* __restrict__ cnt,
    const float* __restrict__ bias, const float* __restrict__ Wlin,
    float* __restrict__ sa, float* __restrict__ sb, int N) {
  const int g = threadIdx.x >> 6;
  const int l = threadIdx.x & 63;
  const int node = blockIdx.x * 4 + g;
  if (node >= N) return;
  const int start = rs[node];
  const int deg = cnt[node];
  float2 acc = make_float2(0.f, 0.f);
  int k = 0;
  for (; k + 4 <= deg; k += 4) {
    int s0 = sorted_src[start + k];
    int s1 = sorted_src[start + k + 1];
    int s2 = sorted_src[start + k + 2];
    int s3 = sorted_src[start + k + 3];
    unsigned v0 = yzu[(size_t)s0 * 128 + l];
    unsigned v1 = yzu[(size_t)s1 * 128 + l];
    unsigned v2 = yzu[(size_t)s2 * 128 + l];
    unsigned v3 = yzu[(size_t)s3 * 128 + l];
    float2 f0 = upk(v0), f1 = upk(v1), f2 = upk(v2), f3 = upk(v3);
    acc.x += (f0.x + f1.x) + (f2.x + f3.x);
    acc.y += (f0.y + f1.y) + (f2.y + f3.y);
  }
  for (; k < deg; ++k) {
    float2 f = upk(yzu[(size_t)sorted_src[start + k] * 128 + l]);
    acc.x += f.x; acc.y += f.y;
  }
  const float inv = 1.f / (float)max(deg, 1);
  float2 z = upk(yzu[(size_t)node * 128 + 64 + l]);
  float hx = acc.x * inv + bias[2 * l] + z.x;
  float hy = acc.y * inv + bias[2 * l + 1] + z.y;
  float pa = hx * Wlin[2 * l] + hy * Wlin[2 * l + 1];
  float pb = hx * Wlin[128 + 2 * l] + hy * Wlin[129 + 2 * l];
#pragma unroll
  for (int off = 32; off > 0; off >>= 1) {
    pa += __shfl_down(pa, off, 64);
    pb += __shfl_down(pb, off, 64);
  }
  if (l == 0) {
    sa[node] = pa;
    sb[node] = pb;
  }
}

// ---------------- edge scoring: out[e] = s_a[i] + s_b[j] + b ----------------
__global__ void score_kernel(const int* __restrict__ idx, int E,
                             const float* __restrict__ sa, const float* __restrict__ sb,
                             const float* __restrict__ blin, float* __restrict__ out) {
  int e = blockIdx.x * 256 + threadIdx.x;
  if (e < E) out[e] = sa[idx[e]] + sb[idx[E + e]] + blin[0];
}

extern "C" void kernel_launch(void* const* d_in, const int* in_sizes, int n_in,
                              void* d_out, int out_size, void* d_ws, size_t ws_size,
                              hipStream_t stream) {
  (void)n_in; (void)out_size; (void)ws_size;
  const float* x    = (const float*)d_in[0];
  const int*   ei   = (const int*)d_in[1];
  const int*   pos  = (const int*)d_in[2];
  const int*   neg  = (const int*)d_in[3];
  const float* Wl1  = (const float*)d_in[4];
  const float* bl1  = (const float*)d_in[5];
  const float* Wr1  = (const float*)d_in[6];
  const float* Wl2  = (const float*)d_in[7];
  const float* bl2  = (const float*)d_in[8];
  const float* Wr2  = (const float*)d_in[9];
  const float* Wlin = (const float*)d_in[10];
  const float* blin = (const float*)d_in[11];

  const int N  = in_sizes[0] / IN_DIM;  // 100000
  const int E  = in_sizes[1] / 2;       // 3200000
  const int Ep = in_sizes[2] / 2;       // 500000
  const int En = in_sizes[3] / 2;       // 500000
  const int* e_src = ei;
  const int* e_dst = ei + E;

  char* ws = (char*)d_ws;
  size_t off = 0;
  auto carve = [&](size_t bytes) -> char* {
    char* p = ws + off;
    off += (bytes + 255) & ~(size_t)255;
    return p;
  };
  const int nbN = (N + 255) / 256;   // 391
  const int NPAD = nbN * 256;        // 100096
  const int nB = (N + NPB - 1) / NPB; // 391 buckets
  const int KS1 = IN_DIM / 32;       // 12
  const int KS2 = HID / 32;          // 4

  int*      cnt    = (int*)carve((size_t)NPAD * 4);
  int*      rs     = (int*)carve((size_t)NPAD * 4);
  int*      partial= (int*)carve(512 * 4);
  int*      base   = (int*)carve(512 * 4);
  int*      bCur   = (int*)carve((size_t)nB * 4);
  unsigned* bData  = (unsigned*)carve((size_t)E * 4);
  int*      sorted = (int*)carve((size_t)E * 4);
  float*    sa     = (float*)carve((size_t)N * 4);
  float*    sb     = (float*)carve((size_t)N * 4);
  _Float16* Bp1    = (_Float16*)carve((size_t)16 * KS1 * 64 * 8 * 2);
  _Float16* Bp2    = (_Float16*)carve((size_t)16 * KS2 * 64 * 8 * 2);
  _Float16* yz     = (_Float16*)carve((size_t)N * 256 * 2);
  _Float16* h1     = (_Float16*)carve((size_t)N * 128 * 2);

  const int nbE = (E + 255) / 256;
  const int gemmBlocks = (N + 127) / 128;
  const int partBlocks = (E + 8191) / 8192;  // 391

  // CSR build
  hipLaunchKernelGGL(zero_i32, dim3(nbN), dim3(256), 0, stream, cnt, NPAD);
  hipLaunchKernelGGL(count_kernel, dim3(nbE), dim3(256), 0, stream, e_dst, E, cnt);
  hipLaunchKernelGGL(scan1, dim3(nbN), dim3(256), 0, stream, cnt, N, rs, partial);
  hipLaunchKernelGGL(scan2, dim3(1), dim3(512), 0, stream, partial, nbN, base);
  hipLaunchKernelGGL(scan3, dim3(nbN), dim3(256), 0, stream, rs, base, N);
  hipLaunchKernelGGL(init_buckets, dim3((nB + 255) / 256), dim3(256), 0, stream, rs, nB, bCur);
  hipLaunchKernelGGL(partition_kernel, dim3(partBlocks), dim3(256), 0, stream,
                     e_src, e_dst, E, nB, bCur, bData);
  hipLaunchKernelGGL(node_sort, dim3(nB), dim3(256), 0, stream, bData, rs, N, E, sorted);

  // weight packing (tiny)
  hipLaunchKernelGGL(pack_w, dim3(8, KS1), dim3(64), 0, stream, Wl1, Bp1, 0);
  hipLaunchKernelGGL(pack_w, dim3(8, KS1), dim3(64), 0, stream, Wr1, Bp1, 8);
  hipLaunchKernelGGL(pack_w, dim3(8, KS2), dim3(64), 0, stream, Wl2, Bp2, 0);
  hipLaunchKernelGGL(pack_w, dim3(8, KS2), dim3(64), 0, stream, Wr2, Bp2, 8);

  // layer 1
  hipLaunchKernelGGL(gemm_f16, dim3(gemmBlocks), dim3(512), 0, stream,
                     x, (const _Float16*)nullptr, N, IN_DIM, Bp1, yz);
  hipLaunchKernelGGL(agg_relu16, dim3((N + 3) / 4), dim3(256), 0, stream,
                     (const unsigned*)yz, sorted, rs, cnt, bl1, (unsigned*)h1, N);
  // layer 2
  hipLaunchKernelGGL(gemm_f16, dim3(gemmBlocks), dim3(512), 0, stream,
                     (const float*)nullptr, h1, N, HID, Bp2, yz);
  hipLaunchKernelGGL(agg_score16, dim3((N + 3) / 4), dim3(256), 0, stream,
                     (const unsigned*)yz, sorted, rs, cnt, bl2, Wlin, sa, sb, N);

  // scoring
  float* out = (float*)d_out;
  hipLaunchKernelGGL(score_kernel, dim3((Ep + 255) / 256), dim3(256), 0, stream,
                     pos, Ep, sa, sb, blin, out);
  hipLaunchKernelGGL(score_kernel, dim3((En + 255) / 256), dim3(256), 0, stream,
                     neg, En, sa, sb, blin, out + Ep);
}

// Round 4
// 667.049 us; speedup vs baseline: 2.0903x; 1.1646x over previous
//
#include <hip/hip_runtime.h>

#define IN_DIM 384
#define HID    128
#define NPB    256            // nodes per bucket (dstLocal fits in 8 bits)

typedef _Float16 half8 __attribute__((ext_vector_type(8)));
typedef float floatx4 __attribute__((ext_vector_type(4)));

// ---------------- utility ----------------
__global__ void zero_i32(int* __restrict__ p, int n) {
  int i = blockIdx.x * 256 + threadIdx.x;
  if (i < n) p[i] = 0;
}

// ---------------- phase 0: coarse bucket histogram (LDS hist, 1 atomic/block/bucket) ----
__global__ __launch_bounds__(256) void bucket_count(
    const int* __restrict__ dst, int E, int nB, int* __restrict__ bucketCnt) {
  __shared__ int hist[391];
  const int t = threadIdx.x;
  const int b0 = blockIdx.x * 8192;
  for (int i = t; i < nB; i += 256) hist[i] = 0;
  __syncthreads();
#pragma unroll
  for (int i = 0; i < 32; ++i) {
    int e = b0 + i * 256 + t;
    if (e < E) atomicAdd(&hist[dst[e] >> 8], 1);
  }
  __syncthreads();
  for (int i = t; i < nB; i += 256) {
    int h = hist[i];
    if (h) atomicAdd(&bucketCnt[i], h);
  }
}

// ---------------- bucket scan: offsets for 391 buckets (single block) ----------------
__global__ void scan_buckets(const int* __restrict__ bucketCnt, int nB, int E, int N,
                             int* __restrict__ bucketBase, int* __restrict__ bCur,
                             int* __restrict__ rs) {
  __shared__ int s[512];
  const int t = threadIdx.x;
  int v = (t < nB) ? bucketCnt[t] : 0;
  s[t] = v;
  __syncthreads();
  for (int off = 1; off < 512; off <<= 1) {
    int y = (t >= off) ? s[t - off] : 0;
    __syncthreads();
    s[t] += y;
    __syncthreads();
  }
  int excl = s[t] - v;
  if (t < nB) {
    bucketBase[t] = excl;
    bCur[t] = excl;
  }
  if (t == nB) bucketBase[nB] = excl;  // == E
  if (t == 0) rs[N] = E;
}

// ---------------- phase 1: partition edges into coarse buckets ----------------
// 8192 edges/block; packed value = (dstLocal << 17) | src  (src < 2^17, dstLocal < 256)
__global__ __launch_bounds__(256) void partition_kernel(
    const int* __restrict__ src, const int* __restrict__ dst, int E, int nB,
    int* __restrict__ bucketCursor, unsigned* __restrict__ bucketData) {
  __shared__ int hist[391];
  __shared__ int gbase[391];
  const int t = threadIdx.x;
  const int b0 = blockIdx.x * 8192;

  for (int i = t; i < nB; i += 256) hist[i] = 0;
  __syncthreads();
#pragma unroll
  for (int i = 0; i < 32; ++i) {
    int e = b0 + i * 256 + t;
    if (e < E) atomicAdd(&hist[dst[e] >> 8], 1);
  }
  __syncthreads();
  for (int i = t; i < nB; i += 256) {
    int h = hist[i];
    gbase[i] = h ? atomicAdd(&bucketCursor[i], h) : 0;
    hist[i] = 0;
  }
  __syncthreads();
#pragma unroll
  for (int i = 0; i < 32; ++i) {
    int e = b0 + i * 256 + t;
    if (e < E) {
      int d = dst[e];
      int b = d >> 8;
      int r = atomicAdd(&hist[b], 1);
      bucketData[gbase[b] + r] = ((unsigned)(d & 255) << 17) | (unsigned)src[e];
    }
  }
}

// ---------------- phase 2: per-bucket node histogram + scan + scatter ----------------
// Writes rs[node] (CSR row pointer) and sorted_src; no global atomics.
__global__ __launch_bounds__(256) void node_sort2(
    const unsigned* __restrict__ bucketData, const int* __restrict__ bucketBase,
    int N, int* __restrict__ sorted_src, int* __restrict__ rs) {
  __shared__ int hist[NPB];
  __shared__ int s[NPB];
  __shared__ int cur[NPB];
  const int b = blockIdx.x;
  const int t = threadIdx.x;
  const int start = bucketBase[b];
  const int end = bucketBase[b + 1];
  hist[t] = 0;
  __syncthreads();
  for (int e = start + t; e < end; e += 256) atomicAdd(&hist[bucketData[e] >> 17], 1);
  __syncthreads();
  int v = hist[t];
  s[t] = v;
  __syncthreads();
  for (int off = 1; off < 256; off <<= 1) {
    int y = (t >= off) ? s[t - off] : 0;
    __syncthreads();
    s[t] += y;
    __syncthreads();
  }
  int excl = s[t] - v;
  const int node = b * NPB + t;
  if (node <= N) rs[node] = start + excl;
  cur[t] = start + excl;
  __syncthreads();
  for (int e = start + t; e < end; e += 256) {
    unsigned d = bucketData[e];
    int p = atomicAdd(&cur[d >> 17], 1);
    sorted_src[p] = (int)(d & 0x1FFFF);
  }
}

// ---------------- weight pack: W[K][128] fp32 -> per-lane MFMA B-fragment order ----------------
__global__ void pack_w(const float* __restrict__ W, _Float16* __restrict__ Bp,
                       int tnBase) {
  const int tn = blockIdx.x;       // 0..7 within this half
  const int ks = blockIdx.y;       // 0..KS-1
  const int KS = gridDim.y;
  const int lane = threadIdx.x;    // 0..63
  const int n = tn * 16 + (lane & 15);
  const int kb = ks * 32 + (lane >> 4) * 8;
  half8 v;
#pragma unroll
  for (int j = 0; j < 8; ++j) v[j] = (_Float16)W[(size_t)(kb + j) * HID + n];
  *(half8*)(Bp + (((size_t)(tnBase + tn) * KS + ks) * 64 + lane) * 8) = v;
}

// ---------------- fp16 MFMA GEMM: C[M x 256] = A[M x K] @ [Bl | Br] ----------------
__global__ __launch_bounds__(512) void gemm_f16(
    const float* __restrict__ A32, const _Float16* __restrict__ A16,
    int M, int K,
    const _Float16* __restrict__ Bp,
    _Float16* __restrict__ C) {
  __shared__ _Float16 As[128][40];

  const int KS = K >> 5;
  const int tid = threadIdx.x;
  const int lane = tid & 63;
  const int wid = tid >> 6;
  const int quad = lane >> 4;
  const int lm = lane & 15;
  const int row0 = (wid & 1) * 64;
  const int ct0 = (wid >> 1) * 4;
  const int blockRow = blockIdx.x * 128;

  const int srow = tid >> 2;
  const int scol = (tid & 3) * 8;

  floatx4 acc[16];
#pragma unroll
  for (int i = 0; i < 16; ++i) {
    acc[i][0] = 0.f; acc[i][1] = 0.f; acc[i][2] = 0.f; acc[i][3] = 0.f;
  }

  for (int ks = 0; ks < KS; ++ks) {
    const int gr = blockRow + srow;
    half8 hv;
    if (A32) {
      float4 f0 = make_float4(0.f, 0.f, 0.f, 0.f), f1 = f0;
      if (gr < M) {
        const float* p = A32 + (size_t)gr * K + ks * 32 + scol;
        f0 = *(const float4*)p;
        f1 = *(const float4*)(p + 4);
      }
      hv[0] = (_Float16)f0.x; hv[1] = (_Float16)f0.y;
      hv[2] = (_Float16)f0.z; hv[3] = (_Float16)f0.w;
      hv[4] = (_Float16)f1.x; hv[5] = (_Float16)f1.y;
      hv[6] = (_Float16)f1.z; hv[7] = (_Float16)f1.w;
    } else {
      if (gr < M) {
        hv = *(const half8*)(A16 + (size_t)gr * K + ks * 32 + scol);
      } else {
#pragma unroll
        for (int j = 0; j < 8; ++j) hv[j] = (_Float16)0.f;
      }
    }
    __syncthreads();
    *(half8*)&As[srow][scol] = hv;
    __syncthreads();

    half8 af[4], bf[4];
#pragma unroll
    for (int rt = 0; rt < 4; ++rt)
      af[rt] = *(const half8*)&As[row0 + rt * 16 + lm][quad * 8];
#pragma unroll
    for (int ct = 0; ct < 4; ++ct) {
      const int tn = ct0 + ct;
      bf[ct] = *(const half8*)(Bp + (((size_t)tn * KS + ks) * 64 + lane) * 8);
    }
#pragma unroll
    for (int rt = 0; rt < 4; ++rt)
#pragma unroll
      for (int ct = 0; ct < 4; ++ct)
        acc[rt * 4 + ct] =
            __builtin_amdgcn_mfma_f32_16x16x32_f16(af[rt], bf[ct], acc[rt * 4 + ct], 0, 0, 0);
  }

#pragma unroll
  for (int rt = 0; rt < 4; ++rt) {
#pragma unroll
    for (int r = 0; r < 4; ++r) {
      const int gm = blockRow + row0 + rt * 16 + quad * 4 + r;
      if (gm < M) {
#pragma unroll
        for (int ct = 0; ct < 4; ++ct) {
          const int col = (ct0 + ct) * 16 + lm;
          C[(size_t)gm * 256 + col] = (_Float16)acc[rt * 4 + ct][r];
        }
      }
    }
  }
}

// ---------------- helpers for fp16-pair math ----------------
__device__ inline float2 upk(unsigned u) {
  union { unsigned v; _Float16 h[2]; } c; c.v = u;
  return make_float2((float)c.h[0], (float)c.h[1]);
}

// ---------------- layer-1 aggregate + combine + ReLU ----------------
// yz viewed as u32: row stride 128 (= 256 fp16). 4 nodes/block, 64 lanes/node.
__global__ __launch_bounds__(256) void agg_relu16(
    const unsigned* __restrict__ yzu, const int* __restrict__ sorted_src,
    const int* __restrict__ rs,
    const float* __restrict__ bias, unsigned* __restrict__ h1u, int N) {
  const int g = threadIdx.x >> 6;
  const int l = threadIdx.x & 63;
  const int node = blockIdx.x * 4 + g;
  if (node >= N) return;
  const int start = rs[node];
  const int deg = rs[node + 1] - start;
  float2 acc = make_float2(0.f, 0.f);
  int k = 0;
  for (; k + 4 <= deg; k += 4) {
    int s0 = sorted_src[start + k];
    int s1 = sorted_src[start + k + 1];
    int s2 = sorted_src[start + k + 2];
    int s3 = sorted_src[start + k + 3];
    unsigned v0 = yzu[(size_t)s0 * 128 + l];
    unsigned v1 = yzu[(size_t)s1 * 128 + l];
    unsigned v2 = yzu[(size_t)s2 * 128 + l];
    unsigned v3 = yzu[(size_t)s3 * 128 + l];
    float2 f0 = upk(v0), f1 = upk(v1), f2 = upk(v2), f3 = upk(v3);
    acc.x += (f0.x + f1.x) + (f2.x + f3.x);
    acc.y += (f0.y + f1.y) + (f2.y + f3.y);
  }
  for (; k < deg; ++k) {
    float2 f = upk(yzu[(size_t)sorted_src[start + k] * 128 + l]);
    acc.x += f.x; acc.y += f.y;
  }
  const float inv = 1.f / (float)max(deg, 1);
  float2 z = upk(yzu[(size_t)node * 128 + 64 + l]);
  float vx = fmaxf(acc.x * inv + bias[2 * l] + z.x, 0.f);
  float vy = fmaxf(acc.y * inv + bias[2 * l + 1] + z.y, 0.f);
  union { unsigned v; _Float16 h[2]; } o;
  o.h[0] = (_Float16)vx; o.h[1] = (_Float16)vy;
  h1u[(size_t)node * 64 + l] = o.v;
}

// ---------------- layer-2 aggregate + combine + fused scorer projection ----------------
__global__ __launch_bounds__(256) void agg_score16(
    const unsigned* __restrict__ yzu, const int* __restrict__ sorted_src,
    const int* __restrict__ rs,
    const float* __restrict__ bias, const float* __restrict__ Wlin,
    float* __restrict__ sa, float* __restrict__ sb, int N) {
  const int g = threadIdx.x >> 6;
  const int l = threadIdx.x & 63;
  const int node = blockIdx.x * 4 + g;
  if (node >= N) return;
  const int start = rs[node];
  const int deg = rs[node + 1] - start;
  float2 acc = make_float2(0.f, 0.f);
  int k = 0;
  for (; k + 4 <= deg; k += 4) {
    int s0 = sorted_src[start + k];
    int s1 = sorted_src[start + k + 1];
    int s2 = sorted_src[start + k + 2];
    int s3 = sorted_src[start + k + 3];
    unsigned v0 = yzu[(size_t)s0 * 128 + l];
    unsigned v1 = yzu[(size_t)s1 * 128 + l];
    unsigned v2 = yzu[(size_t)s2 * 128 + l];
    unsigned v3 = yzu[(size_t)s3 * 128 + l];
    float2 f0 = upk(v0), f1 = upk(v1), f2 = upk(v2), f3 = upk(v3);
    acc.x += (f0.x + f1.x) + (f2.x + f3.x);
    acc.y += (f0.y + f1.y) + (f2.y + f3.y);
  }
  for (; k < deg; ++k) {
    float2 f = upk(yzu[(size_t)sorted_src[start + k] * 128 + l]);
    acc.x += f.x; acc.y += f.y;
  }
  const float inv = 1.f / (float)max(deg, 1);
  float2 z = upk(yzu[(size_t)node * 128 + 64 + l]);
  float hx = acc.x * inv + bias[2 * l] + z.x;
  float hy = acc.y * inv + bias[2 * l + 1] + z.y;
  float pa = hx * Wlin[2 * l] + hy * Wlin[2 * l + 1];
  float pb = hx * Wlin[128 + 2 * l] + hy * Wlin[129 + 2 * l];
#pragma unroll
  for (int off = 32; off > 0; off >>= 1) {
    pa += __shfl_down(pa, off, 64);
    pb += __shfl_down(pb, off, 64);
  }
  if (l == 0) {
    sa[node] = pa;
    sb[node] = pb;
  }
}

// ---------------- edge scoring: out[e] = s_a[i] + s_b[j] + b ----------------
__global__ void score_kernel(const int* __restrict__ idx, int E,
                             const float* __restrict__ sa, const float* __restrict__ sb,
                             const float* __restrict__ blin, float* __restrict__ out) {
  int e = blockIdx.x * 256 + threadIdx.x;
  if (e < E) out[e] = sa[idx[e]] + sb[idx[E + e]] + blin[0];
}

extern "C" void kernel_launch(void* const* d_in, const int* in_sizes, int n_in,
                              void* d_out, int out_size, void* d_ws, size_t ws_size,
                              hipStream_t stream) {
  (void)n_in; (void)out_size; (void)ws_size;
  const float* x    = (const float*)d_in[0];
  const int*   ei   = (const int*)d_in[1];
  const int*   pos  = (const int*)d_in[2];
  const int*   neg  = (const int*)d_in[3];
  const float* Wl1  = (const float*)d_in[4];
  const float* bl1  = (const float*)d_in[5];
  const float* Wr1  = (const float*)d_in[6];
  const float* Wl2  = (const float*)d_in[7];
  const float* bl2  = (const float*)d_in[8];
  const float* Wr2  = (const float*)d_in[9];
  const float* Wlin = (const float*)d_in[10];
  const float* blin = (const float*)d_in[11];

  const int N  = in_sizes[0] / IN_DIM;  // 100000
  const int E  = in_sizes[1] / 2;       // 3200000
  const int Ep = in_sizes[2] / 2;       // 500000
  const int En = in_sizes[3] / 2;       // 500000
  const int* e_src = ei;
  const int* e_dst = ei + E;

  char* ws = (char*)d_ws;
  size_t off = 0;
  auto carve = [&](size_t bytes) -> char* {
    char* p = ws + off;
    off += (bytes + 255) & ~(size_t)255;
    return p;
  };
  const int nB = (N + NPB - 1) / NPB;   // 391 buckets
  const int KS1 = IN_DIM / 32;          // 12
  const int KS2 = HID / 32;             // 4

  int*      rs     = (int*)carve((size_t)(N + 256) * 4);
  int*      bCnt   = (int*)carve(512 * 4);
  int*      bBase  = (int*)carve(512 * 4);
  int*      bCur   = (int*)carve(512 * 4);
  unsigned* bData  = (unsigned*)carve((size_t)E * 4);
  int*      sorted = (int*)carve((size_t)E * 4);
  float*    sa     = (float*)carve((size_t)N * 4);
  float*    sb     = (float*)carve((size_t)N * 4);
  _Float16* Bp1    = (_Float16*)carve((size_t)16 * KS1 * 64 * 8 * 2);
  _Float16* Bp2    = (_Float16*)carve((size_t)16 * KS2 * 64 * 8 * 2);
  _Float16* yz     = (_Float16*)carve((size_t)N * 256 * 2);
  _Float16* h1     = (_Float16*)carve((size_t)N * 128 * 2);

  const int gemmBlocks = (N + 127) / 128;
  const int partBlocks = (E + 8191) / 8192;  // 391

  // CSR build (no per-node global atomics)
  hipLaunchKernelGGL(zero_i32, dim3(2), dim3(256), 0, stream, bCnt, 512);
  hipLaunchKernelGGL(bucket_count, dim3(partBlocks), dim3(256), 0, stream,
                     e_dst, E, nB, bCnt);
  hipLaunchKernelGGL(scan_buckets, dim3(1), dim3(512), 0, stream,
                     bCnt, nB, E, N, bBase, bCur, rs);
  hipLaunchKernelGGL(partition_kernel, dim3(partBlocks), dim3(256), 0, stream,
                     e_src, e_dst, E, nB, bCur, bData);
  hipLaunchKernelGGL(node_sort2, dim3(nB), dim3(256), 0, stream,
                     bData, bBase, N, sorted, rs);

  // weight packing (tiny)
  hipLaunchKernelGGL(pack_w, dim3(8, KS1), dim3(64), 0, stream, Wl1, Bp1, 0);
  hipLaunchKernelGGL(pack_w, dim3(8, KS1), dim3(64), 0, stream, Wr1, Bp1, 8);
  hipLaunchKernelGGL(pack_w, dim3(8, KS2), dim3(64), 0, stream, Wl2, Bp2, 0);
  hipLaunchKernelGGL(pack_w, dim3(8, KS2), dim3(64), 0, stream, Wr2, Bp2, 8);

  // layer 1
  hipLaunchKernelGGL(gemm_f16, dim3(gemmBlocks), dim3(512), 0, stream,
                     x, (const _Float16*)nullptr, N, IN_DIM, Bp1, yz);
  hipLaunchKernelGGL(agg_relu16, dim3((N + 3) / 4), dim3(256), 0, stream,
                     (const unsigned*)yz, sorted, rs, bl1, (unsigned*)h1, N);
  // layer 2
  hipLaunchKernelGGL(gemm_f16, dim3(gemmBlocks), dim3(512), 0, stream,
                     (const float*)nullptr, h1, N, HID, Bp2, yz);
  hipLaunchKernelGGL(agg_score16, dim3((N + 3) / 4), dim3(256), 0, stream,
                     (const unsigned*)yz, sorted, rs, bl2, Wlin, sa, sb, N);

  // scoring
  float* out = (float*)d_out;
  hipLaunchKernelGGL(score_kernel, dim3((Ep + 255) / 256), dim3(256), 0, stream,
                     pos, Ep, sa, sb, blin, out);
  hipLaunchKernelGGL(score_kernel, dim3((En + 255) / 256), dim3(256), 0, stream,
                     neg, En, sa, sb, blin, out + Ep);
}